// Round 7
// baseline (336.832 us; speedup 1.0000x reference)
//
#include <hip/hip_runtime.h>

typedef _Float16 half_t;
typedef half_t half8 __attribute__((ext_vector_type(8)));
typedef half_t half4 __attribute__((ext_vector_type(4)));
typedef float f32x4 __attribute__((ext_vector_type(4)));

#define NAGENT 32768
#define MAXN   16
#define HD     128
#define QCOLS  65
#define QN     (NAGENT * QCOLS)
#define AGB    16                // agents per block
#define EPB    (AGB * MAXN)     // 256 edges per block
#define QROWB  260               // bytes per q-row (65 f32)

// ws layout (half_t element offsets) — f16 transposed weights WT[n][k]
#define O_WMT   0                // [128][64]  W_msg  (k: fn 0..31, ef 32..39, 0-pad)
#define O_WE1E  8192             // [128][64]  W_e1 edge part (fn rows 0..31, ef rows 160..167)
#define O_WE1H  16384            // [128][128] W_e1 h part (rows 32..159)
#define O_WUPD  32768            // [128][160] W_upd
#define O_WX    53248            // [384][128] W_x
#define O_WH    102400           // [384][128] W_h
#define W_TOTAL 151552           // + float hn_wa[NAGENT] right after (4B aligned)

#define MFMA(a, b, c) __builtin_amdgcn_mfma_f32_16x16x32_f16((a), (b), (c), 0, 0, 0)

__global__ void prep_weights(const float* __restrict__ W_msg, const float* __restrict__ W_upd,
                             const float* __restrict__ W_x, const float* __restrict__ W_h,
                             const float* __restrict__ W_e1, half_t* __restrict__ ws) {
    int i = blockIdx.x * 256 + threadIdx.x;
    if (i >= W_TOTAL) return;
    float v; int dst;
    if (i < 8192) {                          // wmT[n][k], Kp=64
        int k = i >> 7, n = i & 127;
        v = (k < 40) ? W_msg[k * HD + n] : 0.f;
        dst = O_WMT + n * 64 + k;
    } else if (i < 16384) {                  // we1eT[n][k]: e1 concat order [fn, h, ef]
        int j = i - 8192; int k = j >> 7, n = j & 127;
        v = (k < 32) ? W_e1[k * HD + n] : (k < 40 ? W_e1[(160 + k - 32) * HD + n] : 0.f);
        dst = O_WE1E + n * 64 + k;
    } else if (i < 32768) {                  // we1hT[n][k] = W_e1 rows 32..159
        int j = i - 16384; int k = j >> 7, n = j & 127;
        v = W_e1[(32 + k) * HD + n];
        dst = O_WE1H + n * 128 + k;
    } else if (i < 53248) {                  // wupdT[n][k], K=160 = [agg|fa]
        int j = i - 32768; int k = j >> 7, n = j & 127;
        v = W_upd[k * HD + n];
        dst = O_WUPD + n * 160 + k;
    } else if (i < 102400) {                 // wxT[n][k], n in [0,384)
        int j = i - 53248; int k = j / 384, n = j - k * 384;
        v = W_x[k * 384 + n];
        dst = O_WX + n * 128 + k;
    } else {
        int j = i - 102400; int k = j / 384, n = j - k * 384;
        v = W_h[k * 384 + n];
        dst = O_WH + n * 128 + k;
    }
    ws[dst] = (half_t)v;
}

__device__ __forceinline__ half8 ldB(const half_t* __restrict__ WT, int kstride, int n0, int k0, int l) {
    return *(const half8*)(WT + (size_t)(n0 + (l & 15)) * kstride + k0 + ((l >> 4) * 8));
}
__device__ __forceinline__ half4 cvt4(float4 v) {
    return (half4){(half_t)v.x, (half_t)v.y, (half_t)v.z, (half_t)v.w};
}
__device__ __forceinline__ half8 cvt8(float4 a, float4 b) {
    return (half8){(half_t)a.x, (half_t)a.y, (half_t)a.z, (half_t)a.w,
                   (half_t)b.x, (half_t)b.y, (half_t)b.z, (half_t)b.w};
}
__device__ __forceinline__ float sigm(float x) { return 1.f / (1.f + __expf(-x)); }
__device__ __forceinline__ float tanh_fast(float x) { return 1.f - 2.f / (__expf(2.f * x) + 1.f); }

// ======================= K1: msg GEMM + segment-sum ========================
// agg[a][0:128] (f16) parked in the q-row region of d_out; K3 overwrites it.
__global__ __launch_bounds__(256, 4) void k_msg(
    const float* __restrict__ feat_nbr, const float* __restrict__ edge_feat,
    const float* __restrict__ b_msg, const int* __restrict__ src_idx,
    const half_t* __restrict__ ws, float* __restrict__ out)
{
    const int t = threadIdx.x;
    const int w = t >> 6, l = t & 63;
    const int l16 = l & 15, q = l >> 4;
    const int a0 = blockIdx.x * AGB;
    const int be = blockIdx.x * EPB;
    const half_t* wmT = ws + O_WMT;
    const half8 hz = {0, 0, 0, 0, 0, 0, 0, 0};

    __shared__ int srcs[EPB];
    srcs[t] = src_idx[be + t];
    __syncthreads();

    half8 B[4][4];                       // hoisted: same B-frags for all agents
    float bm0[4], bm1[4];
    #pragma unroll
    for (int nc = 0; nc < 4; ++nc) {
        const int n0 = nc * 32;
        B[nc][0] = ldB(wmT, 64, n0, 0, l);
        B[nc][1] = ldB(wmT, 64, n0, 32, l);
        B[nc][2] = ldB(wmT, 64, n0 + 16, 0, l);
        B[nc][3] = ldB(wmT, 64, n0 + 16, 32, l);
        bm0[nc] = b_msg[n0 + l16];
        bm1[nc] = b_msg[n0 + 16 + l16];
    }
    #pragma unroll
    for (int mt = 0; mt < 4; ++mt) {
        const int al = w * 4 + mt;
        const int arow = al * 16 + l16;
        const float* fr = feat_nbr + (size_t)srcs[arow] * 32 + q * 8;
        half8 af0 = cvt8(*(const float4*)fr, *(const float4*)(fr + 4));
        half8 af1 = hz;
        if (q == 0) {
            const float* er = edge_feat + (size_t)(be + arow) * 8;
            af1 = cvt8(*(const float4*)er, *(const float4*)(er + 4));
        }
        half_t* arow_out = (half_t*)((char*)out + (size_t)(a0 + al) * QROWB);
        #pragma unroll
        for (int nc = 0; nc < 4; ++nc) {
            f32x4 c0 = {0.f, 0.f, 0.f, 0.f}, c1 = {0.f, 0.f, 0.f, 0.f};
            c0 = MFMA(af0, B[nc][0], c0);
            c0 = MFMA(af1, B[nc][1], c0);
            c1 = MFMA(af0, B[nc][2], c1);
            c1 = MFMA(af1, B[nc][3], c1);
            float s0 = 0.f, s1 = 0.f;
            #pragma unroll
            for (int r = 0; r < 4; ++r) {
                s0 += fmaxf(c0[r] + bm0[nc], 0.f);
                s1 += fmaxf(c1[r] + bm1[nc], 0.f);
            }
            s0 += __shfl_xor(s0, 16); s0 += __shfl_xor(s0, 32);
            s1 += __shfl_xor(s1, 16); s1 += __shfl_xor(s1, 32);
            if (l < 16) {
                arow_out[nc * 32 + l] = (half_t)s0;
                arow_out[nc * 32 + 16 + l] = (half_t)s1;
            }
        }
    }
}

// ============ K2: node update + GRU + che = h_new@We1h + b_e1 ==============
__global__ __launch_bounds__(256, 3) void k_node(
    const float* __restrict__ feat_agent, const float* __restrict__ h_in,
    const float* __restrict__ b_upd, const float* __restrict__ b_ih,
    const float* __restrict__ b_hh, const float* __restrict__ b_e1,
    const float* __restrict__ W_a, half_t* __restrict__ ws,
    float* __restrict__ out)
{
    const int t = threadIdx.x;
    const int w = t >> 6, l = t & 63;
    const int l16 = l & 15, q = l >> 4;
    const int a0 = blockIdx.x * AGB;
    const half_t* wupdT = ws + O_WUPD;
    const half_t* wxT   = ws + O_WX;
    const half_t* whT   = ws + O_WH;
    const half_t* we1hT = ws + O_WE1H;
    float* hn_wa_g = (float*)(ws + W_TOTAL);

    __shared__ half_t A2[AGB][168];      // [agg(0..127) | fa(128..159) | pad]
    __shared__ half_t h_lds[AGB][136];
    __shared__ half_t x_lds[AGB][136];
    __shared__ half_t hn_lds[AGB][136];
    __shared__ float  hnwa[AGB];

    // ---- S0: stage agg (f16, from out q-rows), fa, h ----
    if (t < AGB) hnwa[t] = 0.f;
    {   // agg: 16 rows x 16 chunks of 16B
        int r = t >> 4, c = t & 15;
        half8 v = *(const half8*)((const char*)out + (size_t)(a0 + r) * QROWB + c * 16);
        *(half8*)&A2[r][c * 8] = v;
    }
    if (t < 128) {
        int r = t >> 3, p = t & 7;
        float4 v = ((const float4*)(feat_agent + (size_t)(a0 + r) * 32))[p];
        *(half4*)&A2[r][128 + p * 4] = cvt4(v);
    }
    #pragma unroll
    for (int i = 0; i < 2; ++i) {
        int g = t + 256 * i; int r = g >> 5, c = g & 31;
        float4 v = ((const float4*)(h_in + (size_t)(a0 + r) * HD))[c];
        *(half4*)&h_lds[r][c * 4] = cvt4(v);
    }
    __syncthreads();

    // ---- S2: x = relu([agg|fa]@Wupd + b) ----
    // B-frags batch-loaded BEFORE the MFMA chain: loads issue back-to-back
    // (one ~250cyc L2 latency per batch instead of per load).
    {
        half8 af[5];
        #pragma unroll
        for (int k = 0; k < 5; ++k) af[k] = *(const half8*)&A2[l16][k * 32 + q * 8];
        #pragma unroll
        for (int s = 0; s < 2; ++s) {
            const int n0 = (w * 2 + s) * 16;
            half8 Bu[5];
            #pragma unroll
            for (int k = 0; k < 5; ++k) Bu[k] = ldB(wupdT, 160, n0, k * 32, l);
            f32x4 c = {0.f, 0.f, 0.f, 0.f};
            #pragma unroll
            for (int k = 0; k < 5; ++k) c = MFMA(af[k], Bu[k], c);
            float bu = b_upd[n0 + l16];
            #pragma unroll
            for (int r = 0; r < 4; ++r)
                x_lds[q * 4 + r][n0 + l16] = (half_t)fmaxf(c[r] + bu, 0.f);
        }
    }
    __syncthreads();

    // ---- S3: GRU; fold h_new . W_a[128:256] into per-agent scalar ----
    {
        half8 ax[4], ah[4];
        #pragma unroll
        for (int k = 0; k < 4; ++k) {
            ax[k] = *(const half8*)&x_lds[l16][k * 32 + q * 8];
            ah[k] = *(const half8*)&h_lds[l16][k * 32 + q * 8];
        }
        float pa[4] = {0.f, 0.f, 0.f, 0.f};
        #pragma unroll
        for (int s = 0; s < 2; ++s) {
            const int colb = w * 32 + s * 16;
            f32x4 gi[3], gh[3];
            #pragma unroll
            for (int g = 0; g < 3; ++g) {
                const int n0 = g * 128 + colb;
                half8 Bx[4], Bh[4];      // batched: 8 independent loads in flight
                #pragma unroll
                for (int k = 0; k < 4; ++k) {
                    Bx[k] = ldB(wxT, 128, n0, k * 32, l);
                    Bh[k] = ldB(whT, 128, n0, k * 32, l);
                }
                f32x4 ci = {0.f, 0.f, 0.f, 0.f}, ch = {0.f, 0.f, 0.f, 0.f};
                #pragma unroll
                for (int k = 0; k < 4; ++k) {
                    ci = MFMA(ax[k], Bx[k], ci);
                    ch = MFMA(ah[k], Bh[k], ch);
                }
                gi[g] = ci; gh[g] = ch;
            }
            const int col = colb + l16;
            float bi0 = b_ih[col], bi1 = b_ih[HD + col], bi2 = b_ih[2 * HD + col];
            float bh0 = b_hh[col], bh1 = b_hh[HD + col], bh2 = b_hh[2 * HD + col];
            float wac = W_a[HD + col];
            #pragma unroll
            for (int r = 0; r < 4; ++r) {
                const int row = q * 4 + r;
                float rg = sigm(gi[0][r] + bi0 + gh[0][r] + bh0);
                float zg = sigm(gi[1][r] + bi1 + gh[1][r] + bh1);
                float ng = tanh_fast(gi[2][r] + bi2 + rg * (gh[2][r] + bh2));
                float hv = (1.f - zg) * ng + zg * (float)h_lds[row][col];
                out[QN + (size_t)(a0 + row) * HD + col] = hv;   // output 1: h_new
                hn_lds[row][col] = (half_t)hv;
                pa[r] = fmaf(hv, wac, pa[r]);
            }
        }
        #pragma unroll
        for (int r = 0; r < 4; ++r) {
            #pragma unroll
            for (int m = 1; m <= 8; m <<= 1) pa[r] += __shfl_xor(pa[r], m);
            if (l16 == 0) atomicAdd(&hnwa[q * 4 + r], pa[r]);
        }
    }
    __syncthreads();   // hn_lds + hnwa complete

    // ---- S4h: che = h_new @ We1h + b_e1 -> out q-rows (f16, over agg) ----
    {
        half8 an[4];
        #pragma unroll
        for (int k = 0; k < 4; ++k) an[k] = *(const half8*)&hn_lds[l16][k * 32 + q * 8];
        #pragma unroll
        for (int s = 0; s < 2; ++s) {
            const int n0 = (w * 2 + s) * 16;
            half8 Bh1[4];
            #pragma unroll
            for (int k = 0; k < 4; ++k) Bh1[k] = ldB(we1hT, 128, n0, k * 32, l);
            f32x4 c = {0.f, 0.f, 0.f, 0.f};
            #pragma unroll
            for (int k = 0; k < 4; ++k) c = MFMA(an[k], Bh1[k], c);
            float bv = b_e1[n0 + l16];
            #pragma unroll
            for (int r = 0; r < 4; ++r) {
                half_t* arow_out = (half_t*)((char*)out + (size_t)(a0 + q * 4 + r) * QROWB);
                arow_out[n0 + l16] = (half_t)(c[r] + bv);
            }
        }
    }
    if (t < AGB) hn_wa_g[a0 + t] = hnwa[t];
}

// ====== K3: ze = relu([fn|ef]@We1e + che); q-values + agent scalar =========
__global__ __launch_bounds__(256, 3) void k_edge(
    const float* __restrict__ feat_nbr, const float* __restrict__ edge_feat,
    const float* __restrict__ W_e2, const float* __restrict__ b_e2,
    const float* __restrict__ W_a, const float* __restrict__ b_a,
    const int* __restrict__ src_idx, const half_t* __restrict__ ws,
    float* __restrict__ out)
{
    const int t = threadIdx.x;
    const int w = t >> 6, l = t & 63;
    const int l16 = l & 15, q = l >> 4;
    const int a0 = blockIdx.x * AGB;
    const int be = blockIdx.x * EPB;
    const half_t* we1eT = ws + O_WE1E;
    const float* hn_wa_g = (const float*)(ws + W_TOTAL);
    const half8 hz = {0, 0, 0, 0, 0, 0, 0, 0};

    __shared__ int srcs[EPB];
    srcs[t] = src_idx[be + t];
    __syncthreads();

    half8 B[4][4];
    float wa0[4], wa1[4];
    #pragma unroll
    for (int nc = 0; nc < 4; ++nc) {
        const int n0 = nc * 32;
        B[nc][0] = ldB(we1eT, 64, n0, 0, l);
        B[nc][1] = ldB(we1eT, 64, n0, 32, l);
        B[nc][2] = ldB(we1eT, 64, n0 + 16, 0, l);
        B[nc][3] = ldB(we1eT, 64, n0 + 16, 32, l);
        wa0[nc] = W_a[n0 + l16];
        wa1[nc] = W_a[n0 + 16 + l16];
    }
    const float ba = b_a[0];

    #pragma unroll
    for (int mt = 0; mt < 4; ++mt) {
        const int al = w * 4 + mt;
        const int arow = al * 16 + l16;
        const float* fr = feat_nbr + (size_t)srcs[arow] * 32 + q * 8;
        half8 af0 = cvt8(*(const float4*)fr, *(const float4*)(fr + 4));
        half8 af1 = hz;
        if (q == 0) {
            const float* er = edge_feat + (size_t)(be + arow) * 8;
            af1 = cvt8(*(const float4*)er, *(const float4*)(er + 4));
        }
        const half_t* che_row = (const half_t*)((const char*)out + (size_t)(a0 + al) * QROWB);
        float qa[4][4];
        #pragma unroll
        for (int r = 0; r < 4; ++r)
            #pragma unroll
            for (int p = 0; p < 4; ++p) qa[r][p] = 0.f;
        float wa_part = 0.f;
        #pragma unroll
        for (int nc = 0; nc < 4; ++nc) {
            const int n0 = nc * 32;
            f32x4 c0 = {0.f, 0.f, 0.f, 0.f}, c1 = {0.f, 0.f, 0.f, 0.f};
            c0 = MFMA(af0, B[nc][0], c0);
            c0 = MFMA(af1, B[nc][1], c0);
            c1 = MFMA(af0, B[nc][2], c1);
            c1 = MFMA(af1, B[nc][3], c1);
            const int col0 = n0 + l16, col1 = n0 + 16 + l16;
            float ch0 = (float)che_row[col0], ch1 = (float)che_row[col1];
            float4 w20 = *(const float4*)(W_e2 + col0 * 4);
            float4 w21 = *(const float4*)(W_e2 + col1 * 4);
            float s0 = 0.f, s1 = 0.f;
            #pragma unroll
            for (int r = 0; r < 4; ++r) {
                float z0 = fmaxf(c0[r] + ch0, 0.f);
                float z1 = fmaxf(c1[r] + ch1, 0.f);
                s0 += z0; s1 += z1;
                qa[r][0] = fmaf(z0, w20.x, fmaf(z1, w21.x, qa[r][0]));
                qa[r][1] = fmaf(z0, w20.y, fmaf(z1, w21.y, qa[r][1]));
                qa[r][2] = fmaf(z0, w20.z, fmaf(z1, w21.z, qa[r][2]));
                qa[r][3] = fmaf(z0, w20.w, fmaf(z1, w21.w, qa[r][3]));
            }
            s0 += __shfl_xor(s0, 16); s0 += __shfl_xor(s0, 32);
            s1 += __shfl_xor(s1, 16); s1 += __shfl_xor(s1, 32);
            wa_part = fmaf(s0, wa0[nc], fmaf(s1, wa1[nc], wa_part));
        }
        #pragma unroll
        for (int m = 1; m <= 8; m <<= 1)
            #pragma unroll
            for (int r = 0; r < 4; ++r)
                #pragma unroll
                for (int p = 0; p < 4; ++p) qa[r][p] += __shfl_xor(qa[r][p], m);
        if (l16 < 4) {
            const int p = l16;
            const float bz = b_e2[p];
            #pragma unroll
            for (int r = 0; r < 4; ++r)
                out[(size_t)(a0 + al) * QCOLS + (q * 4 + r) * 4 + p] = qa[r][p] + bz;
        }
        #pragma unroll
        for (int m = 1; m <= 8; m <<= 1) wa_part += __shfl_xor(wa_part, m);
        if (l == 0)
            out[(size_t)(a0 + al) * QCOLS + 64] = wa_part + hn_wa_g[a0 + al] + ba;
    }
}

extern "C" void kernel_launch(void* const* d_in, const int* in_sizes, int n_in,
                              void* d_out, int out_size, void* d_ws, size_t ws_size,
                              hipStream_t stream) {
    const float* feat_nbr   = (const float*)d_in[0];
    const float* feat_agent = (const float*)d_in[1];
    const float* edge_feat  = (const float*)d_in[2];
    const float* h_in       = (const float*)d_in[3];
    const float* W_msg = (const float*)d_in[4];
    const float* b_msg = (const float*)d_in[5];
    const float* W_upd = (const float*)d_in[6];
    const float* b_upd = (const float*)d_in[7];
    const float* W_x   = (const float*)d_in[8];
    const float* W_h   = (const float*)d_in[9];
    const float* b_ih  = (const float*)d_in[10];
    const float* b_hh  = (const float*)d_in[11];
    const float* W_e1  = (const float*)d_in[12];
    const float* b_e1  = (const float*)d_in[13];
    const float* W_e2  = (const float*)d_in[14];
    const float* b_e2  = (const float*)d_in[15];
    const float* W_a   = (const float*)d_in[16];
    const float* b_a   = (const float*)d_in[17];
    const int* src_idx = (const int*)d_in[18];
    // d_in[19] = dst_idx unused: edges grouped by dst, fixed degree 16.
    half_t* ws = (half_t*)d_ws;
    float* out = (float*)d_out;
    const int nblk = NAGENT / AGB;   // 2048

    prep_weights<<<(W_TOTAL + 255) / 256, 256, 0, stream>>>(W_msg, W_upd, W_x, W_h, W_e1, ws);
    k_msg<<<nblk, 256, 0, stream>>>(feat_nbr, edge_feat, b_msg, src_idx, ws, out);
    k_node<<<nblk, 256, 0, stream>>>(feat_agent, h_in, b_upd, b_ih, b_hh, b_e1, W_a, ws, out);
    k_edge<<<nblk, 256, 0, stream>>>(feat_nbr, edge_feat, W_e2, b_e2, W_a, b_a, src_idx, ws, out);
}